// Round 1
// baseline (2812.078 us; speedup 1.0000x reference)
//
#include <hip/hip_runtime.h>
#include <hip/hip_bf16.h>
#include <math.h>

#define BATCH   2
#define T_SEQ   2048
#define DMODEL  1024
#define NHEAD   16
#define HDIM    64
#define QKV_LD  (3*DMODEL)   // 3072

// ---------------------------------------------------------------------------
// Tiled fp32 GEMM: C[M,N] = A[M,K] @ B[K,N].  M,N multiples of 128, K of 8.
// 256 threads, 128x128 block tile, 8x8 per-thread micro-tile, BK=8.
// ---------------------------------------------------------------------------
__global__ __launch_bounds__(256) void gemm128_f32(
    const float* __restrict__ A, const float* __restrict__ B,
    float* __restrict__ C, int M, int N, int K)
{
    __shared__ float As[8][132];   // transposed A tile, +4 pad (16B-aligned rows, bank-spread)
    __shared__ float Bs[8][128];

    const int tid = threadIdx.x;
    const int tx = tid & 15;       // 0..15 -> col group
    const int ty = tid >> 4;       // 0..15 -> row group
    const int m0 = blockIdx.y * 128;
    const int n0 = blockIdx.x * 128;

    // A-tile load mapping: thread loads float4 at (a_m, a_k)
    const int a_m = tid >> 1;            // 0..127
    const int a_k = (tid & 1) * 4;       // 0 or 4
    // B-tile load mapping
    const int b_k = tid >> 5;            // 0..7
    const int b_n = (tid * 4) & 127;

    float acc[8][8];
#pragma unroll
    for (int i = 0; i < 8; i++)
#pragma unroll
        for (int j = 0; j < 8; j++) acc[i][j] = 0.f;

    for (int kt = 0; kt < K; kt += 8) {
        const float4 av = *(const float4*)&A[(size_t)(m0 + a_m) * K + kt + a_k];
        const float4 bv = *(const float4*)&B[(size_t)(kt + b_k) * N + n0 + b_n];
        __syncthreads();   // previous iteration's reads done before overwrite
        As[a_k + 0][a_m] = av.x;
        As[a_k + 1][a_m] = av.y;
        As[a_k + 2][a_m] = av.z;
        As[a_k + 3][a_m] = av.w;
        *(float4*)&Bs[b_k][b_n] = bv;
        __syncthreads();
#pragma unroll
        for (int k = 0; k < 8; k++) {
            float4 a0 = *(float4*)&As[k][ty * 8];
            float4 a1 = *(float4*)&As[k][ty * 8 + 4];
            float4 b0 = *(float4*)&Bs[k][tx * 8];
            float4 b1 = *(float4*)&Bs[k][tx * 8 + 4];
            float ar[8] = {a0.x, a0.y, a0.z, a0.w, a1.x, a1.y, a1.z, a1.w};
            float br[8] = {b0.x, b0.y, b0.z, b0.w, b1.x, b1.y, b1.z, b1.w};
#pragma unroll
            for (int i = 0; i < 8; i++)
#pragma unroll
                for (int j = 0; j < 8; j++)
                    acc[i][j] = fmaf(ar[i], br[j], acc[i][j]);
        }
    }

#pragma unroll
    for (int i = 0; i < 8; i++) {
        const size_t row = (size_t)(m0 + ty * 8 + i) * N + n0 + tx * 8;
        *(float4*)&C[row]     = make_float4(acc[i][0], acc[i][1], acc[i][2], acc[i][3]);
        *(float4*)&C[row + 4] = make_float4(acc[i][4], acc[i][5], acc[i][6], acc[i][7]);
    }
}

// ---------------------------------------------------------------------------
// RoPE in-place on q and k halves of qkv buffer (interleaved-pair rotation).
// One thread per (b,t,h,pair). total = B*T*H*32 = 2^21 threads.
// ---------------------------------------------------------------------------
__global__ __launch_bounds__(256) void rope_kernel(float* __restrict__ qkv)
{
    const int tid = blockIdx.x * blockDim.x + threadIdx.x;
    const int i = tid & 31;            // pair index 0..31
    const int h = (tid >> 5) & 15;
    const int t = (tid >> 9) & 2047;
    const int b = tid >> 20;           // 0..1

    const float inv_freq = powf(10000.f, -(float)(2 * i) / 64.f);
    const float ang = (float)t * inv_freq;
    float s, c;
    sincosf(ang, &s, &c);

    const size_t base = (size_t)(b * T_SEQ + t) * QKV_LD + h * HDIM + 2 * i;
    // q
    {
        float q0 = qkv[base], q1 = qkv[base + 1];
        qkv[base]     = q0 * c - q1 * s;
        qkv[base + 1] = q1 * c + q0 * s;
    }
    // k (offset +1024 columns)
    {
        float k0 = qkv[base + DMODEL], k1 = qkv[base + DMODEL + 1];
        qkv[base + DMODEL]     = k0 * c - k1 * s;
        qkv[base + DMODEL + 1] = k1 * c + k0 * s;
    }
}

// ---------------------------------------------------------------------------
// Causal flash attention. Block = 256 threads = 4 waves; 16 query rows/block
// (4 per wave); K/V tiles of 64 staged in LDS. Online softmax per row.
// out layout: (B,T,H*Dh) = (B,T,D) — matches transpose(0,2,1,3).reshape.
// ---------------------------------------------------------------------------
__global__ __launch_bounds__(256) void attn_kernel(
    const float* __restrict__ qkv, float* __restrict__ out)
{
    __shared__ float Qs[16][65];
    __shared__ float Ks[64][65];
    __shared__ float Vs[64][64];
    __shared__ float Ps[4][64];

    const int tid = threadIdx.x;
    const int lane = tid & 63;
    const int wave = tid >> 6;
    const int bh = blockIdx.y;
    const int b = bh >> 4;
    const int h = bh & 15;
    const int t0 = blockIdx.x * 16;

    // stage Q tile (16 rows x 64)
#pragma unroll
    for (int it = 0; it < 4; it++) {
        const int idx = tid + it * 256;
        const int r = idx >> 6, d = idx & 63;
        Qs[r][d] = qkv[(size_t)(b * T_SEQ + t0 + r) * QKV_LD + h * HDIM + d];
    }

    float m_i[4], l_i[4], o_i[4];
#pragma unroll
    for (int r = 0; r < 4; r++) { m_i[r] = -INFINITY; l_i[r] = 0.f; o_i[r] = 0.f; }

    const int n_tiles = (t0 + 15) / 64 + 1;
    for (int tile = 0; tile < n_tiles; tile++) {
        const int s0 = tile * 64;
        __syncthreads();
        // stage K,V tiles (64 x 64 each)
#pragma unroll
        for (int it = 0; it < 16; it++) {
            const int idx = tid + it * 256;
            const int s = idx >> 6, d = idx & 63;
            const size_t g = (size_t)(b * T_SEQ + s0 + s) * QKV_LD + h * HDIM + d;
            Ks[s][d] = qkv[g + DMODEL];       // k
            Vs[s][d] = qkv[g + 2 * DMODEL];   // v
        }
        __syncthreads();

#pragma unroll
        for (int r = 0; r < 4; r++) {
            const int t = t0 + wave * 4 + r;
            const int s_glob = s0 + lane;
            // score = dot(Q[t], K[s0+lane]) / 8
            float sc = 0.f;
#pragma unroll
            for (int d = 0; d < 64; d++)
                sc = fmaf(Qs[wave * 4 + r][d], Ks[lane][d], sc);
            sc *= 0.125f;
            const bool valid = (s_glob <= t);
            if (!valid) sc = -INFINITY;
            // wave max-reduce
            float mt = sc;
#pragma unroll
            for (int off = 32; off >= 1; off >>= 1)
                mt = fmaxf(mt, __shfl_xor(mt, off));
            const float m_new = fmaxf(m_i[r], mt);
            const float alpha = __expf(m_i[r] - m_new);   // m_i=-inf,m_new finite -> 0
            const float p = valid ? __expf(sc - m_new) : 0.f;
            float S = p;
#pragma unroll
            for (int off = 32; off >= 1; off >>= 1)
                S += __shfl_xor(S, off);
            l_i[r] = l_i[r] * alpha + S;
            m_i[r] = m_new;
            Ps[wave][lane] = p;
            __syncthreads();   // make p visible (also orders vs next r's overwrite)
            // o[d=lane] update
            float o = o_i[r] * alpha;
#pragma unroll
            for (int s4 = 0; s4 < 16; s4++) {
                const float4 pp = *(const float4*)&Ps[wave][s4 * 4];
                o = fmaf(pp.x, Vs[s4 * 4 + 0][lane], o);
                o = fmaf(pp.y, Vs[s4 * 4 + 1][lane], o);
                o = fmaf(pp.z, Vs[s4 * 4 + 2][lane], o);
                o = fmaf(pp.w, Vs[s4 * 4 + 3][lane], o);
            }
            o_i[r] = o;
            __syncthreads();
        }
    }

#pragma unroll
    for (int r = 0; r < 4; r++) {
        const int t = t0 + wave * 4 + r;
        out[(size_t)(b * T_SEQ + t) * DMODEL + h * HDIM + lane] = o_i[r] / l_i[r];
    }
}

// ---------------------------------------------------------------------------
extern "C" void kernel_launch(void* const* d_in, const int* in_sizes, int n_in,
                              void* d_out, int out_size, void* d_ws, size_t ws_size,
                              hipStream_t stream)
{
    const float* x    = (const float*)d_in[0];   // (B,T,D)
    const float* Wqkv = (const float*)d_in[1];   // (D,3D)
    const float* Wout = (const float*)d_in[2];   // (D,D)
    // d_in[3] = attn_mask: deterministically causal triu(k=1); applied analytically.

    float* out = (float*)d_out;

    float* qkv  = (float*)d_ws;                          // 4096*3072 fp32 = 48 MB
    float* attn = qkv + (size_t)BATCH * T_SEQ * QKV_LD;  // 4096*1024 fp32 = 16 MB

    const int M = BATCH * T_SEQ;  // 4096

    // 1) qkv = x @ Wqkv
    {
        dim3 grid(QKV_LD / 128, M / 128);  // (24, 32)
        gemm128_f32<<<grid, 256, 0, stream>>>(x, Wqkv, qkv, M, QKV_LD, DMODEL);
    }
    // 2) RoPE in-place on q,k
    {
        const int total = BATCH * T_SEQ * NHEAD * 32;  // 2^21
        rope_kernel<<<total / 256, 256, 0, stream>>>(qkv);
    }
    // 3) causal flash attention -> attn (B,T,D)
    {
        dim3 grid(T_SEQ / 16, BATCH * NHEAD);  // (128, 32)
        attn_kernel<<<grid, 256, 0, stream>>>(qkv, attn);
    }
    // 4) out = attn @ Wout
    {
        dim3 grid(DMODEL / 128, M / 128);  // (8, 32)
        gemm128_f32<<<grid, 256, 0, stream>>>(attn, Wout, out, M, DMODEL, DMODEL);
    }
}

// Round 2
// 699.995 us; speedup vs baseline: 4.0173x; 4.0173x over previous
//
#include <hip/hip_runtime.h>
#include <math.h>

#define BATCH   2
#define T_SEQ   2048
#define DMODEL  1024
#define NHEAD   16
#define HDIM    64

typedef short s16x8 __attribute__((ext_vector_type(8)));
typedef unsigned short u16x8 __attribute__((ext_vector_type(8)));
typedef float f32x4 __attribute__((ext_vector_type(4)));

// fp32 -> bf16 round-to-nearest-even (bit pattern)
static __device__ __forceinline__ unsigned short f2bf(float f) {
    unsigned int u = __float_as_uint(f);
    u += 0x7fffu + ((u >> 16) & 1u);
    return (unsigned short)(u >> 16);
}

// ---------------------------------------------------------------------------
// Plain tiled fp32 GEMM (used for out = attn @ Wout).
// ---------------------------------------------------------------------------
__global__ __launch_bounds__(256) void gemm128_f32(
    const float* __restrict__ A, const float* __restrict__ B,
    float* __restrict__ C, int M, int N, int K)
{
    __shared__ float As[8][132];
    __shared__ float Bs[8][128];

    const int tid = threadIdx.x;
    const int tx = tid & 15;
    const int ty = tid >> 4;
    const int m0 = blockIdx.y * 128;
    const int n0 = blockIdx.x * 128;

    const int a_m = tid >> 1;
    const int a_k = (tid & 1) * 4;
    const int b_k = tid >> 5;
    const int b_n = (tid * 4) & 127;

    float acc[8][8];
#pragma unroll
    for (int i = 0; i < 8; i++)
#pragma unroll
        for (int j = 0; j < 8; j++) acc[i][j] = 0.f;

    for (int kt = 0; kt < K; kt += 8) {
        const float4 av = *(const float4*)&A[(size_t)(m0 + a_m) * K + kt + a_k];
        const float4 bv = *(const float4*)&B[(size_t)(kt + b_k) * N + n0 + b_n];
        __syncthreads();
        As[a_k + 0][a_m] = av.x;
        As[a_k + 1][a_m] = av.y;
        As[a_k + 2][a_m] = av.z;
        As[a_k + 3][a_m] = av.w;
        *(float4*)&Bs[b_k][b_n] = bv;
        __syncthreads();
#pragma unroll
        for (int k = 0; k < 8; k++) {
            float4 a0 = *(float4*)&As[k][ty * 8];
            float4 a1 = *(float4*)&As[k][ty * 8 + 4];
            float4 b0 = *(float4*)&Bs[k][tx * 8];
            float4 b1 = *(float4*)&Bs[k][tx * 8 + 4];
            float ar[8] = {a0.x, a0.y, a0.z, a0.w, a1.x, a1.y, a1.z, a1.w};
            float br[8] = {b0.x, b0.y, b0.z, b0.w, b1.x, b1.y, b1.z, b1.w};
#pragma unroll
            for (int i = 0; i < 8; i++)
#pragma unroll
                for (int j = 0; j < 8; j++)
                    acc[i][j] = fmaf(ar[i], br[j], acc[i][j]);
        }
    }

#pragma unroll
    for (int i = 0; i < 8; i++) {
        const size_t row = (size_t)(m0 + ty * 8 + i) * N + n0 + tx * 8;
        *(float4*)&C[row]     = make_float4(acc[i][0], acc[i][1], acc[i][2], acc[i][3]);
        *(float4*)&C[row + 4] = make_float4(acc[i][4], acc[i][5], acc[i][6], acc[i][7]);
    }
}

// ---------------------------------------------------------------------------
// QKV GEMM with fused RoPE + 1/sqrt(Dh) scale (Q only) + bf16 pack.
// A = x (4096,1024) fp32, B = Wqkv (1024,3072) fp32.
// Outputs: Qb/Kb/Vb bf16 bits, layout (B,H,T,64).
// ---------------------------------------------------------------------------
__global__ __launch_bounds__(256) void gemm_qkv_rope(
    const float* __restrict__ A, const float* __restrict__ B,
    unsigned short* __restrict__ Qb, unsigned short* __restrict__ Kb,
    unsigned short* __restrict__ Vb)
{
    const int K = DMODEL, N = 3 * DMODEL;
    __shared__ float As[8][132];
    __shared__ float Bs[8][128];

    const int tid = threadIdx.x;
    const int tx = tid & 15;
    const int ty = tid >> 4;
    const int m0 = blockIdx.y * 128;
    const int n0 = blockIdx.x * 128;

    const int a_m = tid >> 1;
    const int a_k = (tid & 1) * 4;
    const int b_k = tid >> 5;
    const int b_n = (tid * 4) & 127;

    float acc[8][8];
#pragma unroll
    for (int i = 0; i < 8; i++)
#pragma unroll
        for (int j = 0; j < 8; j++) acc[i][j] = 0.f;

    for (int kt = 0; kt < K; kt += 8) {
        const float4 av = *(const float4*)&A[(size_t)(m0 + a_m) * K + kt + a_k];
        const float4 bv = *(const float4*)&B[(size_t)(kt + b_k) * N + n0 + b_n];
        __syncthreads();
        As[a_k + 0][a_m] = av.x;
        As[a_k + 1][a_m] = av.y;
        As[a_k + 2][a_m] = av.z;
        As[a_k + 3][a_m] = av.w;
        *(float4*)&Bs[b_k][b_n] = bv;
        __syncthreads();
#pragma unroll
        for (int k = 0; k < 8; k++) {
            float4 a0 = *(float4*)&As[k][ty * 8];
            float4 a1 = *(float4*)&As[k][ty * 8 + 4];
            float4 b0 = *(float4*)&Bs[k][tx * 8];
            float4 b1 = *(float4*)&Bs[k][tx * 8 + 4];
            float ar[8] = {a0.x, a0.y, a0.z, a0.w, a1.x, a1.y, a1.z, a1.w};
            float br[8] = {b0.x, b0.y, b0.z, b0.w, b1.x, b1.y, b1.z, b1.w};
#pragma unroll
            for (int i = 0; i < 8; i++)
#pragma unroll
                for (int j = 0; j < 8; j++)
                    acc[i][j] = fmaf(ar[i], br[j], acc[i][j]);
        }
    }

    // Epilogue: cols n0+tx*8 .. +7 all belong to one part (q/k/v) and one head.
    const int n = n0 + tx * 8;
    const int part = n >> 10;          // 0=q, 1=k, 2=v (uniform per block)
    const int nn = n & 1023;
    const int h = nn >> 6;
    const int d0 = nn & 63;            // multiple of 8
    unsigned short* dst = (part == 0) ? Qb : (part == 1 ? Kb : Vb);

    float invf[4];
    if (part < 2) {
#pragma unroll
        for (int jp = 0; jp < 4; jp++)
            invf[jp] = expf(-(float)(d0 / 2 + jp) * 0.28782313662425572f); // ln(1e4)/32
    }
    const float scale = (part == 0) ? 0.125f : 1.0f;

#pragma unroll
    for (int i = 0; i < 8; i++) {
        const int mrow = m0 + ty * 8 + i;
        const int b = mrow >> 11;
        const int t = mrow & 2047;
        const size_t off = ((size_t)((b * NHEAD + h) * T_SEQ + t)) * HDIM + d0;
        u16x8 res;
        if (part == 2) {
#pragma unroll
            for (int j = 0; j < 8; j++) res[j] = f2bf(acc[i][j]);
        } else {
#pragma unroll
            for (int jp = 0; jp < 4; jp++) {
                float s, c;
                sincosf((float)t * invf[jp], &s, &c);
                const float x0 = acc[i][2 * jp], x1 = acc[i][2 * jp + 1];
                res[2 * jp]     = f2bf((x0 * c - x1 * s) * scale);
                res[2 * jp + 1] = f2bf((x1 * c + x0 * s) * scale);
            }
        }
        *(u16x8*)(dst + off) = res;
    }
}

// ---------------------------------------------------------------------------
// MFMA causal flash attention.
// Block: 256 threads = 4 waves; 64 query rows/block (16/wave); 64-key tiles.
// Layouts (verified, cdna_hip_programming.md §3/§5):
//   A-frag 16x16x32:  A[m=lane&15][k=quad*8+j]
//   B-frag:           B[k=quad*8+j][n=lane&15]
//   C/D:              row=quad*4+reg, col=lane&15
// Q pre-scaled by 0.125 in pack kernel. out: (B,T,D) fp32.
// ---------------------------------------------------------------------------
__global__ __launch_bounds__(256) void attn_mfma(
    const unsigned short* __restrict__ Qb, const unsigned short* __restrict__ Kb,
    const unsigned short* __restrict__ Vb, float* __restrict__ out)
{
    __shared__ __align__(16) unsigned short Ks[64 * 72];      // [s][d], row stride 72
    __shared__ __align__(16) unsigned short Vt[64 * 72];      // [d][s] (transposed)
    __shared__ __align__(16) unsigned short Ps[4][16 * 72];   // per-wave P, [m][s]

    const int tid  = threadIdx.x;
    const int lane = tid & 63;
    const int wave = tid >> 6;
    const int quad = lane >> 4;
    const int lc   = lane & 15;

    const int bh = blockIdx.y;                    // b*16+h
    const int qb = gridDim.x - 1 - blockIdx.x;    // heavy blocks dispatch first
    const int t0 = qb * 64;
    const size_t head_base = (size_t)bh * T_SEQ * HDIM;

    // Q fragments (A-layout), rows t0 + wave*16 + lc
    s16x8 qf0, qf1;
    {
        const size_t qrow = head_base + (size_t)(t0 + wave * 16 + lc) * HDIM;
        qf0 = *(const s16x8*)(Qb + qrow + quad * 8);
        qf1 = *(const s16x8*)(Qb + qrow + 32 + quad * 8);
    }

    f32x4 o[4];                 // O[m=quad*4+reg][d=nb2*16+lc]
    float m_i[4], l_i[4];
#pragma unroll
    for (int r = 0; r < 4; r++) {
        o[r][0] = o[r][1] = o[r][2] = o[r][3] = 0.f;  // note: o[nb2][r] used below
        m_i[r] = -INFINITY;
        l_i[r] = 0.f;
    }

    const int sst  = tid >> 2;          // staging row 0..63
    const int sd0  = (tid & 3) * 16;    // staging col base

    const int n_tiles = qb + 1;
    for (int tile = 0; tile < n_tiles; ++tile) {
        const int s0 = tile * 64;
        // issue global loads before the barrier (overlap with prior compute)
        const size_t g = head_base + (size_t)(s0 + sst) * HDIM + sd0;
        const s16x8 k0 = *(const s16x8*)(Kb + g);
        const s16x8 k1 = *(const s16x8*)(Kb + g + 8);
        const s16x8 v0 = *(const s16x8*)(Vb + g);
        const s16x8 v1 = *(const s16x8*)(Vb + g + 8);
        __syncthreads();   // prior tile's LDS reads complete
        *(s16x8*)&Ks[sst * 72 + sd0]     = k0;
        *(s16x8*)&Ks[sst * 72 + sd0 + 8] = k1;
#pragma unroll
        for (int e = 0; e < 8; e++) Vt[(sd0 + e) * 72 + sst]     = ((const unsigned short*)&v0)[e];
#pragma unroll
        for (int e = 0; e < 8; e++) Vt[(sd0 + 8 + e) * 72 + sst] = ((const unsigned short*)&v1)[e];
        __syncthreads();

        // S = Q K^T  (4 col-blocks of 16, K=64 via 2 MFMAs each)
        f32x4 sacc[4];
#pragma unroll
        for (int nb = 0; nb < 4; nb++) {
            sacc[nb][0] = sacc[nb][1] = sacc[nb][2] = sacc[nb][3] = 0.f;
            const s16x8 b0 = *(const s16x8*)&Ks[(nb * 16 + lc) * 72 + quad * 8];
            const s16x8 b1 = *(const s16x8*)&Ks[(nb * 16 + lc) * 72 + 32 + quad * 8];
            sacc[nb] = __builtin_amdgcn_mfma_f32_16x16x32_bf16(qf0, b0, sacc[nb], 0, 0, 0);
            sacc[nb] = __builtin_amdgcn_mfma_f32_16x16x32_bf16(qf1, b1, sacc[nb], 0, 0, 0);
        }

        // causal mask: only the diagonal tile needs it (s0 == t0)
        if (s0 == t0) {
#pragma unroll
            for (int nb = 0; nb < 4; nb++) {
                const int sg = nb * 16 + lc;
#pragma unroll
                for (int r = 0; r < 4; r++) {
                    const int tg = wave * 16 + quad * 4 + r;
                    if (sg > tg) sacc[nb][r] = -INFINITY;
                }
            }
        }

        // online softmax, per row (reg r), reduce across the 16-lane quad group
#pragma unroll
        for (int r = 0; r < 4; r++) {
            float mt = fmaxf(fmaxf(sacc[0][r], sacc[1][r]), fmaxf(sacc[2][r], sacc[3][r]));
            mt = fmaxf(mt, __shfl_xor(mt, 1));
            mt = fmaxf(mt, __shfl_xor(mt, 2));
            mt = fmaxf(mt, __shfl_xor(mt, 4));
            mt = fmaxf(mt, __shfl_xor(mt, 8));
            const float mn = fmaxf(m_i[r], mt);
            const float alpha = __expf(m_i[r] - mn);
            m_i[r] = mn;
            float rs = 0.f;
#pragma unroll
            for (int nb = 0; nb < 4; nb++) {
                const float p = __expf(sacc[nb][r] - mn);
                sacc[nb][r] = p;
                rs += p;
            }
            rs += __shfl_xor(rs, 1);
            rs += __shfl_xor(rs, 2);
            rs += __shfl_xor(rs, 4);
            rs += __shfl_xor(rs, 8);
            l_i[r] = l_i[r] * alpha + rs;
#pragma unroll
            for (int nb2 = 0; nb2 < 4; nb2++) o[nb2][r] *= alpha;
        }

        // P (C-layout) -> LDS -> A-layout for PV
        unsigned short* pw = &Ps[wave][0];
#pragma unroll
        for (int r = 0; r < 4; r++)
#pragma unroll
            for (int nb = 0; nb < 4; nb++)
                pw[(quad * 4 + r) * 72 + nb * 16 + lc] = f2bf(sacc[nb][r]);
        __syncthreads();

        const s16x8 pa0 = *(const s16x8*)&Ps[wave][lc * 72 + quad * 8];
        const s16x8 pa1 = *(const s16x8*)&Ps[wave][lc * 72 + 32 + quad * 8];
#pragma unroll
        for (int nb2 = 0; nb2 < 4; nb2++) {
            const s16x8 vb0 = *(const s16x8*)&Vt[(nb2 * 16 + lc) * 72 + quad * 8];
            const s16x8 vb1 = *(const s16x8*)&Vt[(nb2 * 16 + lc) * 72 + 32 + quad * 8];
            o[nb2] = __builtin_amdgcn_mfma_f32_16x16x32_bf16(pa0, vb0, o[nb2], 0, 0, 0);
            o[nb2] = __builtin_amdgcn_mfma_f32_16x16x32_bf16(pa1, vb1, o[nb2], 0, 0, 0);
        }
    }

    // epilogue: out[b][t][h*64+d] = O/l
    const int b = bh >> 4;
    const int h = bh & 15;
#pragma unroll
    for (int r = 0; r < 4; r++) {
        const int t = t0 + wave * 16 + quad * 4 + r;
        const float inv_l = 1.f / l_i[r];
        float* orow = out + ((size_t)(b * T_SEQ + t)) * DMODEL + h * HDIM + lc;
#pragma unroll
        for (int nb2 = 0; nb2 < 4; nb2++)
            orow[nb2 * 16] = o[nb2][r] * inv_l;
    }
}

// ---------------------------------------------------------------------------
extern "C" void kernel_launch(void* const* d_in, const int* in_sizes, int n_in,
                              void* d_out, int out_size, void* d_ws, size_t ws_size,
                              hipStream_t stream)
{
    const float* x    = (const float*)d_in[0];   // (B,T,D)
    const float* Wqkv = (const float*)d_in[1];   // (D,3D)
    const float* Wout = (const float*)d_in[2];   // (D,D)
    // d_in[3] attn_mask: causal triu(k=1), applied analytically.

    float* out = (float*)d_out;

    // ws layout (40 MiB total, ws_size >= 64 MiB proven in round 1):
    //   [0,16M):  attn fp32 (B,T,D)
    //   [16,24M): Qb bf16 (B,H,T,64), pre-scaled 0.125, RoPE'd
    //   [24,32M): Kb bf16, RoPE'd
    //   [32,40M): Vb bf16
    float* attn = (float*)d_ws;
    unsigned short* Qb = (unsigned short*)((char*)d_ws + (16u << 20));
    unsigned short* Kb = (unsigned short*)((char*)d_ws + (24u << 20));
    unsigned short* Vb = (unsigned short*)((char*)d_ws + (32u << 20));

    const int M = BATCH * T_SEQ;  // 4096

    // 1) qkv GEMM + RoPE + scale + bf16 pack
    {
        dim3 grid(3 * DMODEL / 128, M / 128);  // (24, 32)
        gemm_qkv_rope<<<grid, 256, 0, stream>>>(x, Wqkv, Qb, Kb, Vb);
    }
    // 2) MFMA causal flash attention -> attn (B,T,D) fp32
    {
        dim3 grid(T_SEQ / 64, BATCH * NHEAD);  // (32, 32)
        attn_mfma<<<grid, 256, 0, stream>>>(Qb, Kb, Vb, attn);
    }
    // 3) out = attn @ Wout
    {
        dim3 grid(DMODEL / 128, M / 128);  // (8, 32)
        gemm128_f32<<<grid, 256, 0, stream>>>(attn, Wout, out, M, DMODEL, DMODEL);
    }
}

// Round 3
// 306.388 us; speedup vs baseline: 9.1781x; 2.2847x over previous
//
#include <hip/hip_runtime.h>
#include <math.h>

#define BATCH   2
#define T_SEQ   2048
#define DMODEL  1024
#define NHEAD   16
#define HDIM    64

typedef short s16x8 __attribute__((ext_vector_type(8)));
typedef unsigned short u16x8 __attribute__((ext_vector_type(8)));
typedef float f32x4 __attribute__((ext_vector_type(4)));

typedef const unsigned int __attribute__((address_space(1))) GUI;
typedef unsigned int __attribute__((address_space(3))) LUI;

// fp32 -> bf16 round-to-nearest-even (bit pattern)
static __device__ __forceinline__ unsigned short f2bf(float f) {
    unsigned int u = __float_as_uint(f);
    u += 0x7fffu + ((u >> 16) & 1u);
    return (unsigned short)(u >> 16);
}

// ---------------------------------------------------------------------------
// x fp32 -> bf16, 8 elems/thread
// ---------------------------------------------------------------------------
__global__ __launch_bounds__(256) void convert_f32_bf16(
    const float* __restrict__ src, unsigned short* __restrict__ dst)
{
    const int i = blockIdx.x * 256 + threadIdx.x;
    const float4 a = ((const float4*)src)[2 * i];
    const float4 b = ((const float4*)src)[2 * i + 1];
    u16x8 r;
    r[0] = f2bf(a.x); r[1] = f2bf(a.y); r[2] = f2bf(a.z); r[3] = f2bf(a.w);
    r[4] = f2bf(b.x); r[5] = f2bf(b.y); r[6] = f2bf(b.z); r[7] = f2bf(b.w);
    ((u16x8*)dst)[i] = r;
}

// ---------------------------------------------------------------------------
// dst[c][r] = bf16(src[r][c]).  src (R,C) fp32 row-major -> dst (C,R) bf16.
// 64x64 tiles, 256 threads.
// ---------------------------------------------------------------------------
__global__ __launch_bounds__(256) void transpose_f32_bf16(
    const float* __restrict__ src, unsigned short* __restrict__ dst, int R, int C)
{
    __shared__ unsigned short tile[64][68];
    const int tc0 = blockIdx.x * 64;   // src col tile
    const int tr0 = blockIdx.y * 64;   // src row tile
    const int tx = threadIdx.x & 63;
    const int ty = threadIdx.x >> 6;   // 0..3
#pragma unroll
    for (int i = 0; i < 16; i++) {
        const int rr = i * 4 + ty;
        tile[tx][rr] = f2bf(src[(size_t)(tr0 + rr) * C + tc0 + tx]);
    }
    __syncthreads();
#pragma unroll
    for (int i = 0; i < 16; i++) {
        const int cc = i * 4 + ty;
        dst[(size_t)(tc0 + cc) * R + tr0 + tx] = tile[cc][tx];
    }
}

// ---------------------------------------------------------------------------
// Shared MFMA GEMM main loop (m97 structure): C128x128 = A[M,K] x Bt[N,K]^T,
// bf16 inputs, BK=32, 256 threads = 4 waves (each 64x64), global_load_lds(16B).
// LDS tiles [128][32] bf16 row-major, unpadded (global_load_lds constraint).
// acc[mt][nb] C-layout: row = quad*4+r, col = lc.
// ---------------------------------------------------------------------------
__device__ __forceinline__ void mfma_gemm_loop(
    const unsigned short* __restrict__ A, const unsigned short* __restrict__ Bt,
    unsigned short* As, unsigned short* Bs,
    int m0, int n0, int K, f32x4 acc[4][4])
{
    const int tid  = threadIdx.x;
    const int wave = tid >> 6;
    const int lane = tid & 63;
    const int quad = lane >> 4;
    const int lc   = lane & 15;
    const int wr   = (wave >> 1) * 64;
    const int wc   = (wave & 1) * 64;

    // staging: 8 chunks of 1024B per tile; wave w stages chunks {2w, 2w+1}
    const int c0    = wave * 2;
    const int srow0 = c0 * 16 + (lane >> 2);   // + 16 for second chunk
    const int scol  = (lane & 3) * 8;

#pragma unroll
    for (int i = 0; i < 4; i++)
#pragma unroll
        for (int j = 0; j < 4; j++)
            acc[i][j] = (f32x4){0.f, 0.f, 0.f, 0.f};

    for (int kt = 0; kt < K; kt += 32) {
        // issue direct-to-LDS loads for this K-slice
        {
            const unsigned short* ga0 = A + (size_t)(m0 + srow0) * K + kt + scol;
            const unsigned short* ga1 = A + (size_t)(m0 + srow0 + 16) * K + kt + scol;
            const unsigned short* gb0 = Bt + (size_t)(n0 + srow0) * K + kt + scol;
            const unsigned short* gb1 = Bt + (size_t)(n0 + srow0 + 16) * K + kt + scol;
            __builtin_amdgcn_global_load_lds((GUI*)ga0, (LUI*)(As + c0 * 512 + lane * 8), 16, 0, 0);
            __builtin_amdgcn_global_load_lds((GUI*)ga1, (LUI*)(As + (c0 + 1) * 512 + lane * 8), 16, 0, 0);
            __builtin_amdgcn_global_load_lds((GUI*)gb0, (LUI*)(Bs + c0 * 512 + lane * 8), 16, 0, 0);
            __builtin_amdgcn_global_load_lds((GUI*)gb1, (LUI*)(Bs + (c0 + 1) * 512 + lane * 8), 16, 0, 0);
        }
        __syncthreads();   // drains vmcnt(0): tile staged; prev reads done via trailing barrier

        s16x8 a[4], b[4];
#pragma unroll
        for (int mt = 0; mt < 4; mt++)
            a[mt] = *(const s16x8*)(As + (wr + mt * 16 + lc) * 32 + quad * 8);
#pragma unroll
        for (int nb = 0; nb < 4; nb++)
            b[nb] = *(const s16x8*)(Bs + (wc + nb * 16 + lc) * 32 + quad * 8);
#pragma unroll
        for (int mt = 0; mt < 4; mt++)
#pragma unroll
            for (int nb = 0; nb < 4; nb++)
                acc[mt][nb] = __builtin_amdgcn_mfma_f32_16x16x32_bf16(a[mt], b[nb], acc[mt][nb], 0, 0, 0);
        __syncthreads();   // frag reads done before next overwrite
    }
}

// ---------------------------------------------------------------------------
// QKV GEMM (bf16 MFMA) + fused RoPE + 0.125 Q-scale + pack to (B,H,T,64) bf16.
// ---------------------------------------------------------------------------
__global__ __launch_bounds__(256) void gemm_qkv_rope_mfma(
    const unsigned short* __restrict__ xb, const unsigned short* __restrict__ Wt,
    unsigned short* __restrict__ Qb, unsigned short* __restrict__ Kb,
    unsigned short* __restrict__ Vb)
{
    __shared__ __align__(16) unsigned short As[128 * 32];
    __shared__ __align__(16) unsigned short Bs[128 * 32];

    const int m0 = blockIdx.y * 128;
    const int n0 = blockIdx.x * 128;
    f32x4 acc[4][4];
    mfma_gemm_loop(xb, Wt, As, Bs, m0, n0, DMODEL, acc);

    const int lane = threadIdx.x & 63;
    const int wave = threadIdx.x >> 6;
    const int quad = lane >> 4;
    const int lc   = lane & 15;
    const int wr   = (wave >> 1) * 64;
    const int wc   = (wave & 1) * 64;

    const int n_base = n0 + wc;          // multiple of 64; part/head uniform-ish
    const int part = n_base >> 10;       // 0=q 1=k 2=v, uniform per block
    unsigned short* dst = (part == 0) ? Qb : (part == 1 ? Kb : Vb);
    const float scale = (part == 0) ? 0.125f : 1.0f;

#pragma unroll
    for (int nb = 0; nb < 4; nb++) {
        const int n = n_base + nb * 16 + lc;
        const int h = (n >> 6) & 15;
        const int d = n & 63;
        const size_t hb = (size_t)h * T_SEQ * HDIM + d;
        if (part == 2) {
#pragma unroll
            for (int mt = 0; mt < 4; mt++) {
                const int mb = m0 + wr + mt * 16 + quad * 4;
#pragma unroll
                for (int r = 0; r < 4; r++) {
                    const int m = mb + r;
                    const int bb = m >> 11, t = m & 2047;
                    dst[(size_t)bb * NHEAD * T_SEQ * HDIM + hb + (size_t)t * HDIM] =
                        f2bf(acc[mt][nb][r]);
                }
            }
        } else {
            const float inv_freq = exp2f(-(float)(d >> 1) * 0.415241011861f); // log2(1e4)/32
            const float ssign = (lc & 1) ? 1.f : -1.f;
#pragma unroll
            for (int mt = 0; mt < 4; mt++) {
                const int mb = m0 + wr + mt * 16 + quad * 4;
#pragma unroll
                for (int r = 0; r < 4; r++) {
                    const float val = acc[mt][nb][r];
                    const float prt = __shfl_xor(val, 1);
                    const int m = mb + r;
                    const int bb = m >> 11, t = m & 2047;
                    float s, c;
                    __sincosf((float)t * inv_freq, &s, &c);
                    const float res = fmaf(prt, ssign * s, val * c) * scale;
                    dst[(size_t)bb * NHEAD * T_SEQ * HDIM + hb + (size_t)t * HDIM] = f2bf(res);
                }
            }
        }
    }
}

// ---------------------------------------------------------------------------
// Out-proj GEMM (bf16 MFMA): out[M,N] fp32 = attnb[M,K] x Wout_t[N,K]^T
// ---------------------------------------------------------------------------
__global__ __launch_bounds__(256) void gemm_out_mfma(
    const unsigned short* __restrict__ A, const unsigned short* __restrict__ Bt,
    float* __restrict__ C, int N, int K)
{
    __shared__ __align__(16) unsigned short As[128 * 32];
    __shared__ __align__(16) unsigned short Bs[128 * 32];

    const int m0 = blockIdx.y * 128;
    const int n0 = blockIdx.x * 128;
    f32x4 acc[4][4];
    mfma_gemm_loop(A, Bt, As, Bs, m0, n0, K, acc);

    const int lane = threadIdx.x & 63;
    const int wave = threadIdx.x >> 6;
    const int quad = lane >> 4;
    const int lc   = lane & 15;
    const int wr   = (wave >> 1) * 64;
    const int wc   = (wave & 1) * 64;

#pragma unroll
    for (int mt = 0; mt < 4; mt++) {
        const int mb = m0 + wr + mt * 16 + quad * 4;
#pragma unroll
        for (int r = 0; r < 4; r++) {
            float* row = C + (size_t)(mb + r) * N + n0 + wc;
#pragma unroll
            for (int nb = 0; nb < 4; nb++)
                row[nb * 16 + lc] = acc[mt][nb][r];
        }
    }
}

// ---------------------------------------------------------------------------
// MFMA causal flash attention (round-2 verified; epilogue now emits bf16).
// ---------------------------------------------------------------------------
__global__ __launch_bounds__(256) void attn_mfma(
    const unsigned short* __restrict__ Qb, const unsigned short* __restrict__ Kb,
    const unsigned short* __restrict__ Vb, unsigned short* __restrict__ out)
{
    __shared__ __align__(16) unsigned short Ks[64 * 72];      // [s][d]
    __shared__ __align__(16) unsigned short Vt[64 * 72];      // [d][s]
    __shared__ __align__(16) unsigned short Ps[4][16 * 72];   // per-wave P [m][s]

    const int tid  = threadIdx.x;
    const int lane = tid & 63;
    const int wave = tid >> 6;
    const int quad = lane >> 4;
    const int lc   = lane & 15;

    const int bh = blockIdx.y;
    const int qb = gridDim.x - 1 - blockIdx.x;    // heavy blocks first
    const int t0 = qb * 64;
    const size_t head_base = (size_t)bh * T_SEQ * HDIM;

    s16x8 qf0, qf1;
    {
        const size_t qrow = head_base + (size_t)(t0 + wave * 16 + lc) * HDIM;
        qf0 = *(const s16x8*)(Qb + qrow + quad * 8);
        qf1 = *(const s16x8*)(Qb + qrow + 32 + quad * 8);
    }

    f32x4 o[4];
    float m_i[4], l_i[4];
#pragma unroll
    for (int r = 0; r < 4; r++) {
        o[r][0] = o[r][1] = o[r][2] = o[r][3] = 0.f;
        m_i[r] = -INFINITY;
        l_i[r] = 0.f;
    }

    const int sst = tid >> 2;
    const int sd0 = (tid & 3) * 16;

    const int n_tiles = qb + 1;
    for (int tile = 0; tile < n_tiles; ++tile) {
        const int s0 = tile * 64;
        const size_t g = head_base + (size_t)(s0 + sst) * HDIM + sd0;
        const s16x8 k0 = *(const s16x8*)(Kb + g);
        const s16x8 k1 = *(const s16x8*)(Kb + g + 8);
        const s16x8 v0 = *(const s16x8*)(Vb + g);
        const s16x8 v1 = *(const s16x8*)(Vb + g + 8);
        __syncthreads();
        *(s16x8*)&Ks[sst * 72 + sd0]     = k0;
        *(s16x8*)&Ks[sst * 72 + sd0 + 8] = k1;
#pragma unroll
        for (int e = 0; e < 8; e++) Vt[(sd0 + e) * 72 + sst]     = ((const unsigned short*)&v0)[e];
#pragma unroll
        for (int e = 0; e < 8; e++) Vt[(sd0 + 8 + e) * 72 + sst] = ((const unsigned short*)&v1)[e];
        __syncthreads();

        f32x4 sacc[4];
#pragma unroll
        for (int nb = 0; nb < 4; nb++) {
            sacc[nb][0] = sacc[nb][1] = sacc[nb][2] = sacc[nb][3] = 0.f;
            const s16x8 b0 = *(const s16x8*)&Ks[(nb * 16 + lc) * 72 + quad * 8];
            const s16x8 b1 = *(const s16x8*)&Ks[(nb * 16 + lc) * 72 + 32 + quad * 8];
            sacc[nb] = __builtin_amdgcn_mfma_f32_16x16x32_bf16(qf0, b0, sacc[nb], 0, 0, 0);
            sacc[nb] = __builtin_amdgcn_mfma_f32_16x16x32_bf16(qf1, b1, sacc[nb], 0, 0, 0);
        }

        if (s0 == t0) {
#pragma unroll
            for (int nb = 0; nb < 4; nb++) {
                const int sg = nb * 16 + lc;
#pragma unroll
                for (int r = 0; r < 4; r++) {
                    const int tg = wave * 16 + quad * 4 + r;
                    if (sg > tg) sacc[nb][r] = -INFINITY;
                }
            }
        }

#pragma unroll
        for (int r = 0; r < 4; r++) {
            float mt = fmaxf(fmaxf(sacc[0][r], sacc[1][r]), fmaxf(sacc[2][r], sacc[3][r]));
            mt = fmaxf(mt, __shfl_xor(mt, 1));
            mt = fmaxf(mt, __shfl_xor(mt, 2));
            mt = fmaxf(mt, __shfl_xor(mt, 4));
            mt = fmaxf(mt, __shfl_xor(mt, 8));
            const float mn = fmaxf(m_i[r], mt);
            const float alpha = __expf(m_i[r] - mn);
            m_i[r] = mn;
            float rs = 0.f;
#pragma unroll
            for (int nb = 0; nb < 4; nb++) {
                const float p = __expf(sacc[nb][r] - mn);
                sacc[nb][r] = p;
                rs += p;
            }
            rs += __shfl_xor(rs, 1);
            rs += __shfl_xor(rs, 2);
            rs += __shfl_xor(rs, 4);
            rs += __shfl_xor(rs, 8);
            l_i[r] = l_i[r] * alpha + rs;
#pragma unroll
            for (int nb2 = 0; nb2 < 4; nb2++) o[nb2][r] *= alpha;
        }

        unsigned short* pw = &Ps[wave][0];
#pragma unroll
        for (int r = 0; r < 4; r++)
#pragma unroll
            for (int nb = 0; nb < 4; nb++)
                pw[(quad * 4 + r) * 72 + nb * 16 + lc] = f2bf(sacc[nb][r]);
        __syncthreads();

        const s16x8 pa0 = *(const s16x8*)&Ps[wave][lc * 72 + quad * 8];
        const s16x8 pa1 = *(const s16x8*)&Ps[wave][lc * 72 + 32 + quad * 8];
#pragma unroll
        for (int nb2 = 0; nb2 < 4; nb2++) {
            const s16x8 vb0 = *(const s16x8*)&Vt[(nb2 * 16 + lc) * 72 + quad * 8];
            const s16x8 vb1 = *(const s16x8*)&Vt[(nb2 * 16 + lc) * 72 + 32 + quad * 8];
            o[nb2] = __builtin_amdgcn_mfma_f32_16x16x32_bf16(pa0, vb0, o[nb2], 0, 0, 0);
            o[nb2] = __builtin_amdgcn_mfma_f32_16x16x32_bf16(pa1, vb1, o[nb2], 0, 0, 0);
        }
    }

    const int b = bh >> 4;
    const int h = bh & 15;
#pragma unroll
    for (int r = 0; r < 4; r++) {
        const int t = t0 + wave * 16 + quad * 4 + r;
        const float inv_l = 1.f / l_i[r];
        unsigned short* orow = out + ((size_t)(b * T_SEQ + t)) * DMODEL + h * HDIM + lc;
#pragma unroll
        for (int nb2 = 0; nb2 < 4; nb2++)
            orow[nb2 * 16] = f2bf(o[nb2][r] * inv_l);
    }
}

// ---------------------------------------------------------------------------
extern "C" void kernel_launch(void* const* d_in, const int* in_sizes, int n_in,
                              void* d_out, int out_size, void* d_ws, size_t ws_size,
                              hipStream_t stream)
{
    const float* x    = (const float*)d_in[0];   // (B,T,D) fp32
    const float* Wqkv = (const float*)d_in[1];   // (D,3D) fp32
    const float* Wout = (const float*)d_in[2];   // (D,D) fp32
    // d_in[3] attn_mask: causal triu(k=1), applied analytically.

    float* out = (float*)d_out;

    // ws layout (48 MiB; 64 MiB proven available):
    char* ws = (char*)d_ws;
    unsigned short* attnb  = (unsigned short*)(ws);               // (B,T,D) bf16, 8 MB
    unsigned short* Qb     = (unsigned short*)(ws + (8u  << 20)); // (B,H,T,64) bf16
    unsigned short* Kb     = (unsigned short*)(ws + (16u << 20));
    unsigned short* Vb     = (unsigned short*)(ws + (24u << 20));
    unsigned short* xb     = (unsigned short*)(ws + (32u << 20)); // (M,K) bf16, 8 MB
    unsigned short* Wqkv_t = (unsigned short*)(ws + (40u << 20)); // (3D,D) bf16, 6 MB
    unsigned short* Wout_t = (unsigned short*)(ws + (46u << 20)); // (D,D) bf16, 2 MB

    const int M = BATCH * T_SEQ;  // 4096

    // 0) convert / transpose inputs to bf16
    convert_f32_bf16<<<(M * DMODEL / 8) / 256, 256, 0, stream>>>(x, xb);
    transpose_f32_bf16<<<dim3(3 * DMODEL / 64, DMODEL / 64), 256, 0, stream>>>(Wqkv, Wqkv_t, DMODEL, 3 * DMODEL);
    transpose_f32_bf16<<<dim3(DMODEL / 64, DMODEL / 64), 256, 0, stream>>>(Wout, Wout_t, DMODEL, DMODEL);

    // 1) QKV MFMA GEMM + RoPE + scale + pack
    gemm_qkv_rope_mfma<<<dim3(3 * DMODEL / 128, M / 128), 256, 0, stream>>>(xb, Wqkv_t, Qb, Kb, Vb);

    // 2) MFMA causal flash attention -> attnb (B,T,D) bf16
    attn_mfma<<<dim3(T_SEQ / 64, BATCH * NHEAD), 256, 0, stream>>>(Qb, Kb, Vb, attnb);

    // 3) out = attnb @ Wout  (fp32 out)
    gemm_out_mfma<<<dim3(DMODEL / 128, M / 128), 256, 0, stream>>>(attnb, Wout_t, out, DMODEL, DMODEL);
}

// Round 4
// 230.185 us; speedup vs baseline: 12.2166x; 1.3311x over previous
//
#include <hip/hip_runtime.h>
#include <math.h>

#define BATCH   2
#define T_SEQ   2048
#define DMODEL  1024
#define NHEAD   16
#define HDIM    64

typedef short s16x8 __attribute__((ext_vector_type(8)));
typedef unsigned short u16x8 __attribute__((ext_vector_type(8)));
typedef unsigned short u16x4 __attribute__((ext_vector_type(4)));
typedef float f32x4 __attribute__((ext_vector_type(4)));

typedef const unsigned int __attribute__((address_space(1))) GUI;
typedef unsigned int __attribute__((address_space(3))) LUI;

// fp32 -> bf16 round-to-nearest-even (bit pattern)
static __device__ __forceinline__ unsigned short f2bf(float f) {
    unsigned int u = __float_as_uint(f);
    u += 0x7fffu + ((u >> 16) & 1u);
    return (unsigned short)(u >> 16);
}

// ---------------------------------------------------------------------------
// x fp32 -> bf16, 8 elems/thread
// ---------------------------------------------------------------------------
__global__ __launch_bounds__(256) void convert_f32_bf16(
    const float* __restrict__ src, unsigned short* __restrict__ dst)
{
    const int i = blockIdx.x * 256 + threadIdx.x;
    const float4 a = ((const float4*)src)[2 * i];
    const float4 b = ((const float4*)src)[2 * i + 1];
    u16x8 r;
    r[0] = f2bf(a.x); r[1] = f2bf(a.y); r[2] = f2bf(a.z); r[3] = f2bf(a.w);
    r[4] = f2bf(b.x); r[5] = f2bf(b.y); r[6] = f2bf(b.z); r[7] = f2bf(b.w);
    ((u16x8*)dst)[i] = r;
}

// ---------------------------------------------------------------------------
// dst[c][r] = bf16(src[r][c]).  src (R,C) fp32 row-major -> dst (C,R) bf16.
// ---------------------------------------------------------------------------
__global__ __launch_bounds__(256) void transpose_f32_bf16(
    const float* __restrict__ src, unsigned short* __restrict__ dst, int R, int C)
{
    __shared__ unsigned short tile[64][68];
    const int tc0 = blockIdx.x * 64;
    const int tr0 = blockIdx.y * 64;
    const int tx = threadIdx.x & 63;
    const int ty = threadIdx.x >> 6;
#pragma unroll
    for (int i = 0; i < 16; i++) {
        const int rr = i * 4 + ty;
        tile[tx][rr] = f2bf(src[(size_t)(tr0 + rr) * C + tc0 + tx]);
    }
    __syncthreads();
#pragma unroll
    for (int i = 0; i < 16; i++) {
        const int cc = i * 4 + ty;
        dst[(size_t)(tc0 + cc) * R + tr0 + tx] = tile[cc][tx];
    }
}

// ---------------------------------------------------------------------------
// Shared MFMA GEMM main loop (m97 structure): C128x128 = A[M,K] x Bt[N,K]^T.
// ---------------------------------------------------------------------------
__device__ __forceinline__ void mfma_gemm_loop(
    const unsigned short* __restrict__ A, const unsigned short* __restrict__ Bt,
    unsigned short* As, unsigned short* Bs,
    int m0, int n0, int K, f32x4 acc[4][4])
{
    const int tid  = threadIdx.x;
    const int wave = tid >> 6;
    const int lane = tid & 63;
    const int quad = lane >> 4;
    const int lc   = lane & 15;
    const int wr   = (wave >> 1) * 64;
    const int wc   = (wave & 1) * 64;

    const int c0    = wave * 2;
    const int srow0 = c0 * 16 + (lane >> 2);
    const int scol  = (lane & 3) * 8;

#pragma unroll
    for (int i = 0; i < 4; i++)
#pragma unroll
        for (int j = 0; j < 4; j++)
            acc[i][j] = (f32x4){0.f, 0.f, 0.f, 0.f};

    for (int kt = 0; kt < K; kt += 32) {
        {
            const unsigned short* ga0 = A + (size_t)(m0 + srow0) * K + kt + scol;
            const unsigned short* ga1 = A + (size_t)(m0 + srow0 + 16) * K + kt + scol;
            const unsigned short* gb0 = Bt + (size_t)(n0 + srow0) * K + kt + scol;
            const unsigned short* gb1 = Bt + (size_t)(n0 + srow0 + 16) * K + kt + scol;
            __builtin_amdgcn_global_load_lds((GUI*)ga0, (LUI*)(As + c0 * 512 + lane * 8), 16, 0, 0);
            __builtin_amdgcn_global_load_lds((GUI*)ga1, (LUI*)(As + (c0 + 1) * 512 + lane * 8), 16, 0, 0);
            __builtin_amdgcn_global_load_lds((GUI*)gb0, (LUI*)(Bs + c0 * 512 + lane * 8), 16, 0, 0);
            __builtin_amdgcn_global_load_lds((GUI*)gb1, (LUI*)(Bs + (c0 + 1) * 512 + lane * 8), 16, 0, 0);
        }
        __syncthreads();

        s16x8 a[4], b[4];
#pragma unroll
        for (int mt = 0; mt < 4; mt++)
            a[mt] = *(const s16x8*)(As + (wr + mt * 16 + lc) * 32 + quad * 8);
#pragma unroll
        for (int nb = 0; nb < 4; nb++)
            b[nb] = *(const s16x8*)(Bs + (wc + nb * 16 + lc) * 32 + quad * 8);
#pragma unroll
        for (int mt = 0; mt < 4; mt++)
#pragma unroll
            for (int nb = 0; nb < 4; nb++)
                acc[mt][nb] = __builtin_amdgcn_mfma_f32_16x16x32_bf16(a[mt], b[nb], acc[mt][nb], 0, 0, 0);
        __syncthreads();
    }
}

// ---------------------------------------------------------------------------
// QKV GEMM (bf16 MFMA) + fused RoPE + 0.125 Q-scale + pack.
// Q,K -> (B,H,T,64);  V -> TRANSPOSED (B,H,64,T) for the attention kernel.
// ---------------------------------------------------------------------------
__global__ __launch_bounds__(256) void gemm_qkv_rope_mfma(
    const unsigned short* __restrict__ xb, const unsigned short* __restrict__ Wt,
    unsigned short* __restrict__ Qb, unsigned short* __restrict__ Kb,
    unsigned short* __restrict__ Vb)
{
    __shared__ __align__(16) unsigned short As[128 * 32];
    __shared__ __align__(16) unsigned short Bs[128 * 32];

    const int m0 = blockIdx.y * 128;
    const int n0 = blockIdx.x * 128;
    f32x4 acc[4][4];
    mfma_gemm_loop(xb, Wt, As, Bs, m0, n0, DMODEL, acc);

    const int lane = threadIdx.x & 63;
    const int wave = threadIdx.x >> 6;
    const int quad = lane >> 4;
    const int lc   = lane & 15;
    const int wr   = (wave >> 1) * 64;
    const int wc   = (wave & 1) * 64;

    const int n_base = n0 + wc;
    const int part = n_base >> 10;       // 0=q 1=k 2=v, uniform per block
    unsigned short* dst = (part == 0) ? Qb : (part == 1 ? Kb : Vb);
    const float scale = (part == 0) ? 0.125f : 1.0f;

#pragma unroll
    for (int nb = 0; nb < 4; nb++) {
        const int n = n_base + nb * 16 + lc;
        const int h = (n >> 6) & 15;
        const int d = n & 63;
        if (part == 2) {
            // V^T layout: (B,H,64,T)
#pragma unroll
            for (int mt = 0; mt < 4; mt++) {
                const int mb = m0 + wr + mt * 16 + quad * 4;
#pragma unroll
                for (int r = 0; r < 4; r++) {
                    const int m = mb + r;
                    const int bb = m >> 11, t = m & 2047;
                    dst[((size_t)(bb * NHEAD + h) * HDIM + d) * T_SEQ + t] =
                        f2bf(acc[mt][nb][r]);
                }
            }
        } else {
            const size_t hb = (size_t)h * T_SEQ * HDIM + d;
            const float inv_freq = exp2f(-(float)(d >> 1) * 0.415241011861f); // log2(1e4)/32
            const float ssign = (lc & 1) ? 1.f : -1.f;
#pragma unroll
            for (int mt = 0; mt < 4; mt++) {
                const int mb = m0 + wr + mt * 16 + quad * 4;
#pragma unroll
                for (int r = 0; r < 4; r++) {
                    const float val = acc[mt][nb][r];
                    const float prt = __shfl_xor(val, 1);
                    const int m = mb + r;
                    const int bb = m >> 11, t = m & 2047;
                    float s, c;
                    __sincosf((float)t * inv_freq, &s, &c);
                    const float res = fmaf(prt, ssign * s, val * c) * scale;
                    dst[(size_t)bb * NHEAD * T_SEQ * HDIM + hb + (size_t)t * HDIM] = f2bf(res);
                }
            }
        }
    }
}

// ---------------------------------------------------------------------------
// Out-proj GEMM (bf16 MFMA): out[M,N] fp32 = attnb[M,K] x Wout_t[N,K]^T
// ---------------------------------------------------------------------------
__global__ __launch_bounds__(256) void gemm_out_mfma(
    const unsigned short* __restrict__ A, const unsigned short* __restrict__ Bt,
    float* __restrict__ C, int N, int K)
{
    __shared__ __align__(16) unsigned short As[128 * 32];
    __shared__ __align__(16) unsigned short Bs[128 * 32];

    const int m0 = blockIdx.y * 128;
    const int n0 = blockIdx.x * 128;
    f32x4 acc[4][4];
    mfma_gemm_loop(A, Bt, As, Bs, m0, n0, K, acc);

    const int lane = threadIdx.x & 63;
    const int wave = threadIdx.x >> 6;
    const int quad = lane >> 4;
    const int lc   = lane & 15;
    const int wr   = (wave >> 1) * 64;
    const int wc   = (wave & 1) * 64;

#pragma unroll
    for (int mt = 0; mt < 4; mt++) {
        const int mb = m0 + wr + mt * 16 + quad * 4;
#pragma unroll
        for (int r = 0; r < 4; r++) {
            float* row = C + (size_t)(mb + r) * N + n0 + wc;
#pragma unroll
            for (int nb = 0; nb < 4; nb++)
                row[nb * 16 + lc] = acc[mt][nb][r];
        }
    }
}

// ---------------------------------------------------------------------------
// MFMA causal flash attention v2 — S^T/O^T formulation, lane-local softmax.
// Block: 256 threads = 4 waves; each wave owns 32 q-rows (2 subtiles of 16);
// block covers 128 q-rows.  64-key tiles staged async via global_load_lds
// into unpadded [64][64] LDS with XOR-granule swizzle (applied on the global
// source address, so lane-contiguity and coalescing both hold).
//
// Verified layout facts used (same physical LDS reads as the round-2/3
// kernel, MFMA argument order swapped → transposed C):
//   A[m=lc][k=quad*8+j], B[k=quad*8+j][n=lc], C[row=quad*4+r][col=lc]
//   S^T = MFMA(K_frag, Q_frag):  S^T[key=quad*4+r][qrow=lc]
//   O^T = MFMA(Vt_frag, Pt_frag): O^T[d=quad*4+r][qrow=lc]
// Softmax state (m, l, alpha) is per-qrow = per-lane -> no broadcasts.
// ---------------------------------------------------------------------------
__global__ __launch_bounds__(256) void attn_mfma2(
    const unsigned short* __restrict__ Qb, const unsigned short* __restrict__ Kb,
    const unsigned short* __restrict__ Vtg, unsigned short* __restrict__ out)
{
    __shared__ __align__(16) unsigned short Ks[64 * 64];   // [key][d], swizzled
    __shared__ __align__(16) unsigned short Vs[64 * 64];   // [d][key], swizzled
    __shared__ __align__(16) unsigned short Ps[4][16 * 72];// per-wave P [qrow][key]

    const int tid  = threadIdx.x;
    const int lane = tid & 63;
    const int wave = tid >> 6;
    const int quad = lane >> 4;
    const int lc   = lane & 15;
    const int rsw  = lc & 7;             // frag-read swizzle key

    const int bh = blockIdx.y;           // b*16+h
    // pair-balance: blocks y and y^16 (likely co-resident) get complementary work
    const int qb = (blockIdx.y & 16) ? (15 - blockIdx.x) : blockIdx.x;
    const int t0 = qb * 128;
    const size_t headK = (size_t)bh * T_SEQ * HDIM;   // K: (BH,T,64)
    const size_t headV = (size_t)bh * HDIM * T_SEQ;   // Vt: (BH,64,T)

    // Q fragments (used as B operand): qf[su][kc]
    s16x8 qf[2][2];
#pragma unroll
    for (int su = 0; su < 2; su++) {
        const size_t qrow = headK + (size_t)(t0 + wave * 32 + su * 16 + lc) * HDIM;
        qf[su][0] = *(const s16x8*)(Qb + qrow + quad * 8);
        qf[su][1] = *(const s16x8*)(Qb + qrow + 32 + quad * 8);
    }

    f32x4 o[2][4];            // O^T[su][db]: rows d=db*16+quad*4+r, col qrow=lc
    float m_i[2], l_i[2];
#pragma unroll
    for (int su = 0; su < 2; su++) {
        m_i[su] = -INFINITY;
        l_i[su] = 0.f;
#pragma unroll
        for (int db = 0; db < 4; db++)
            o[su][db] = (f32x4){0.f, 0.f, 0.f, 0.f};
    }

    // staging geometry: 8 chunks of 1 KiB (8 rows x 128 B) per 64x64 tile;
    // wave w stages chunks {2w, 2w+1} of both K and Vt.
    const int c0   = wave * 2;
    const int krow = lane >> 3;              // row within chunk, 0..7
    const int d8sw = (lane & 7) ^ krow;      // swizzled source granule
    unsigned short* pw = Ps[wave];

    const int n_tiles = 2 * qb + 2;
    for (int tile = 0; tile < n_tiles; ++tile) {
        const int s0 = tile * 64;
        __syncthreads();   // all waves done reading previous tile's Ks/Vs
        {
            const unsigned short* gk0 = Kb + headK + (size_t)(s0 + c0 * 8 + krow) * HDIM + d8sw * 8;
            const unsigned short* gk1 = Kb + headK + (size_t)(s0 + c0 * 8 + 8 + krow) * HDIM + d8sw * 8;
            const unsigned short* gv0 = Vtg + headV + (size_t)(c0 * 8 + krow) * T_SEQ + s0 + d8sw * 8;
            const unsigned short* gv1 = Vtg + headV + (size_t)(c0 * 8 + 8 + krow) * T_SEQ + s0 + d8sw * 8;
            __builtin_amdgcn_global_load_lds((GUI*)gk0, (LUI*)(Ks + c0 * 512 + lane * 8), 16, 0, 0);
            __builtin_amdgcn_global_load_lds((GUI*)gk1, (LUI*)(Ks + (c0 + 1) * 512 + lane * 8), 16, 0, 0);
            __builtin_amdgcn_global_load_lds((GUI*)gv0, (LUI*)(Vs + c0 * 512 + lane * 8), 16, 0, 0);
            __builtin_amdgcn_global_load_lds((GUI*)gv1, (LUI*)(Vs + (c0 + 1) * 512 + lane * 8), 16, 0, 0);
        }
        __syncthreads();   // tile staged (compiler drains vmcnt before barrier)

        // S^T = K x Q^T : st[kb][su], keys kb*16+quad*4+r, qrow = su*16+lc
        f32x4 st[4][2];
#pragma unroll
        for (int kb = 0; kb < 4; kb++) {
            const s16x8 ka0 = *(const s16x8*)&Ks[(kb * 16 + lc) * 64 + ((quad ^ rsw) * 8)];
            const s16x8 ka1 = *(const s16x8*)&Ks[(kb * 16 + lc) * 64 + (((4 + quad) ^ rsw) * 8)];
#pragma unroll
            for (int su = 0; su < 2; su++) {
                f32x4 z = (f32x4){0.f, 0.f, 0.f, 0.f};
                z = __builtin_amdgcn_mfma_f32_16x16x32_bf16(ka0, qf[su][0], z, 0, 0, 0);
                z = __builtin_amdgcn_mfma_f32_16x16x32_bf16(ka1, qf[su][1], z, 0, 0, 0);
                st[kb][su] = z;
            }
        }

        // V^T fragments for PV (A operand), reused by both subtiles
        s16x8 va[4][2];
#pragma unroll
        for (int db = 0; db < 4; db++) {
            va[db][0] = *(const s16x8*)&Vs[(db * 16 + lc) * 64 + ((quad ^ rsw) * 8)];
            va[db][1] = *(const s16x8*)&Vs[(db * 16 + lc) * 64 + (((4 + quad) ^ rsw) * 8)];
        }

        // causal mask — only tiles overlapping the diagonal band
        if (s0 >= t0) {
#pragma unroll
            for (int kb = 0; kb < 4; kb++) {
                const int key = s0 + kb * 16 + quad * 4;
#pragma unroll
                for (int su = 0; su < 2; su++) {
                    const int qrow = t0 + wave * 32 + su * 16 + lc;
#pragma unroll
                    for (int r = 0; r < 4; r++)
                        if (key + r > qrow) st[kb][su][r] = -INFINITY;
                }
            }
        }

        // per-subtile: lane-local online softmax, P^T pack->LDS (wave-local,
        // no barrier), PV MFMAs
#pragma unroll
        for (int su = 0; su < 2; su++) {
            float mt = st[0][su][0];
#pragma unroll
            for (int kb = 0; kb < 4; kb++)
#pragma unroll
                for (int r = 0; r < 4; r++) mt = fmaxf(mt, st[kb][su][r]);
            mt = fmaxf(mt, __shfl_xor(mt, 16));
            mt = fmaxf(mt, __shfl_xor(mt, 32));
            const float mn = fmaxf(m_i[su], mt);
            const float alpha = __expf(m_i[su] - mn);
            m_i[su] = mn;
            float rs = 0.f;
#pragma unroll
            for (int kb = 0; kb < 4; kb++)
#pragma unroll
                for (int r = 0; r < 4; r++) {
                    const float p = __expf(st[kb][su][r] - mn);
                    st[kb][su][r] = p;
                    rs += p;
                }
            rs += __shfl_xor(rs, 16);
            rs += __shfl_xor(rs, 32);
            l_i[su] = l_i[su] * alpha + rs;
#pragma unroll
            for (int db = 0; db < 4; db++) {
                o[su][db][0] *= alpha; o[su][db][1] *= alpha;
                o[su][db][2] *= alpha; o[su][db][3] *= alpha;
            }
            // store P (un-transposing): Ps[qrow=lc][key], b64 per kb
#pragma unroll
            for (int kb = 0; kb < 4; kb++) {
                u16x4 pk;
                pk[0] = f2bf(st[kb][su][0]); pk[1] = f2bf(st[kb][su][1]);
                pk[2] = f2bf(st[kb][su][2]); pk[3] = f2bf(st[kb][su][3]);
                *(u16x4*)&pw[lc * 72 + kb * 16 + quad * 4] = pk;
            }
            // read P^T fragments (B operand) — same-wave DS ordering, no barrier
            const s16x8 pb0 = *(const s16x8*)&pw[lc * 72 + quad * 8];
            const s16x8 pb1 = *(const s16x8*)&pw[lc * 72 + 32 + quad * 8];
#pragma unroll
            for (int db = 0; db < 4; db++) {
                o[su][db] = __builtin_amdgcn_mfma_f32_16x16x32_bf16(va[db][0], pb0, o[su][db], 0, 0, 0);
                o[su][db] = __builtin_amdgcn_mfma_f32_16x16x32_bf16(va[db][1], pb1, o[su][db], 0, 0, 0);
            }
        }
    }

    // epilogue: out[b][t][h*64+d] = O^T[d][qrow]/l, b64 stores (r-contiguous)
    const int b = bh >> 4;
    const int h = bh & 15;
#pragma unroll
    for (int su = 0; su < 2; su++) {
        const float inv_l = 1.f / l_i[su];
        const int t = t0 + wave * 32 + su * 16 + lc;
        unsigned short* orow = out + (size_t)(b * T_SEQ + t) * DMODEL + h * HDIM + quad * 4;
#pragma unroll
        for (int db = 0; db < 4; db++) {
            u16x4 pk;
            pk[0] = f2bf(o[su][db][0] * inv_l); pk[1] = f2bf(o[su][db][1] * inv_l);
            pk[2] = f2bf(o[su][db][2] * inv_l); pk[3] = f2bf(o[su][db][3] * inv_l);
            *(u16x4*)(orow + db * 16) = pk;
        }
    }
}

// ---------------------------------------------------------------------------
extern "C" void kernel_launch(void* const* d_in, const int* in_sizes, int n_in,
                              void* d_out, int out_size, void* d_ws, size_t ws_size,
                              hipStream_t stream)
{
    const float* x    = (const float*)d_in[0];   // (B,T,D) fp32
    const float* Wqkv = (const float*)d_in[1];   // (D,3D) fp32
    const float* Wout = (const float*)d_in[2];   // (D,D) fp32
    // d_in[3] attn_mask: causal triu(k=1), applied analytically.

    float* out = (float*)d_out;

    char* ws = (char*)d_ws;
    unsigned short* attnb  = (unsigned short*)(ws);               // (B,T,D) bf16, 8 MB
    unsigned short* Qb     = (unsigned short*)(ws + (8u  << 20)); // (B,H,T,64)
    unsigned short* Kb     = (unsigned short*)(ws + (16u << 20)); // (B,H,T,64)
    unsigned short* Vt     = (unsigned short*)(ws + (24u << 20)); // (B,H,64,T)
    unsigned short* xb     = (unsigned short*)(ws + (32u << 20)); // (M,K) bf16
    unsigned short* Wqkv_t = (unsigned short*)(ws + (40u << 20)); // (3D,D) bf16
    unsigned short* Wout_t = (unsigned short*)(ws + (46u << 20)); // (D,D) bf16

    const int M = BATCH * T_SEQ;  // 4096

    // 0) convert / transpose inputs to bf16
    convert_f32_bf16<<<(M * DMODEL / 8) / 256, 256, 0, stream>>>(x, xb);
    transpose_f32_bf16<<<dim3(3 * DMODEL / 64, DMODEL / 64), 256, 0, stream>>>(Wqkv, Wqkv_t, DMODEL, 3 * DMODEL);
    transpose_f32_bf16<<<dim3(DMODEL / 64, DMODEL / 64), 256, 0, stream>>>(Wout, Wout_t, DMODEL, DMODEL);

    // 1) QKV MFMA GEMM + RoPE + scale + pack (V transposed)
    gemm_qkv_rope_mfma<<<dim3(3 * DMODEL / 128, M / 128), 256, 0, stream>>>(xb, Wqkv_t, Qb, Kb, Vt);

    // 2) MFMA causal flash attention v2 -> attnb (B,T,D) bf16
    attn_mfma2<<<dim3(T_SEQ / 128, BATCH * NHEAD), 256, 0, stream>>>(Qb, Kb, Vt, attnb);

    // 3) out = attnb @ Wout  (fp32 out)
    gemm_out_mfma<<<dim3(DMODEL / 128, M / 128), 256, 0, stream>>>(attnb, Wout_t, out, DMODEL, DMODEL);
}